// Round 8
// baseline (565.488 us; speedup 1.0000x reference)
//
#include <hip/hip_runtime.h>
#include <math.h>

// Problem constants
constexpr int B_ = 8192;   // batch rows
constexpr int D_ = 1024;   // per-expert dim
constexpr int M_ = 8;      // experts
constexpr int H_ = 256;    // gate hidden

// GEMM1: cat[8192 x 8192] @ W1[8192 x 256], fp32 via bf16-triple MFMA emulation
constexpr int SPLITK = 4;
constexpr int KSP = 2048;          // K per split (16-chunks never straddle expert boundary)
constexpr int BM = 32, BK = 16;    // BM=32 -> grid 256x4 = 1024 blocks = 4 blocks/CU
constexpr int NCH = KSP / BK;      // 128 chunks per block
constexpr int NG  = (M_ * D_) / BK; // 512 global 16-k chunks

typedef __bf16 bf16x8 __attribute__((ext_vector_type(8)));
typedef float  f32x16 __attribute__((ext_vector_type(16)));
typedef short  short8 __attribute__((ext_vector_type(8)));

__device__ __forceinline__ unsigned short f2bf(float x) {
    unsigned int u = __float_as_uint(x);
    u += 0x7FFFu + ((u >> 16) & 1u);           // round-to-nearest-even
    return (unsigned short)(u >> 16);
}
__device__ __forceinline__ float bf2f(unsigned short s) {
    return __uint_as_float(((unsigned int)s) << 16);
}

#define MFMA(A, Bf, C) __builtin_amdgcn_mfma_f32_32x32x16_bf16((A), (Bf), (C), 0, 0, 0)

// ---------------------------------------------------------------------------
// splitw1: precompute W1's h/m/l bf16 decomposition ONCE, packed per-chunk:
// P[g][ks][n][8] (g = 16-k chunk, ks = k-half, n = column). gemm1 waves then
// load their private B fragments STRAIGHT to registers (B is never shared
// across waves -- LDS round-trip for B was pure overhead).
// ---------------------------------------------------------------------------
__global__ __launch_bounds__(256)
void splitw1_kernel(const float* __restrict__ W1, short* __restrict__ Ph,
                    short* __restrict__ Pm, short* __restrict__ Pl)
{
    const int g = blockIdx.x;          // 16-k chunk
    const int t = threadIdx.x;         // column n
    float v[16];
#pragma unroll
    for (int k = 0; k < 16; ++k) v[k] = W1[(size_t)(g * 16 + k) * H_ + t];
#pragma unroll
    for (int ks = 0; ks < 2; ++ks) {
        short8 vh, vm, vl;
#pragma unroll
        for (int j = 0; j < 8; ++j) {
            const float x = v[ks * 8 + j];
            const unsigned short h = f2bf(x);
            float r = x - bf2f(h);
            const unsigned short m = f2bf(r);
            r = r - bf2f(m);
            const unsigned short l = f2bf(r);
            vh[j] = (short)h; vm[j] = (short)m; vl[j] = (short)l;
        }
        const size_t o = ((size_t)(g * 2 + ks) * 256 + t) * 8;
        *(short8*)&Ph[o] = vh;
        *(short8*)&Pm[o] = vm;
        *(short8*)&Pl[o] = vl;
    }
}

// ---------------------------------------------------------------------------
// GEMM1 v5: BM=32, 512 threads (8 waves x 32-col strips), grid 256x4 = 1024
// blocks = 4 blocks/CU = 8 waves/SIMD (100% occupancy; VGPR must stay <=64,
// est ~55). One f32x16 acc per wave. A through LDS (6 KB double-buffered,
// 3 ds_read_b128/wave/chunk); B global->reg, reg-double-buffered across the
// barrier. One barrier per chunk. fp32 emulated as 6 bf16 passes
// (hh, hm, mh, mm, hl, lh) -- bit-identical to v3/v4.
// ---------------------------------------------------------------------------
__global__ __launch_bounds__(512, 8)
void gemm1_kernel(const float* __restrict__ zs,
                  const short* __restrict__ Ph,
                  const short* __restrict__ Pm,
                  const short* __restrict__ Pl,
                  float* __restrict__ part)
{
    // A chunk image(ks,m): idx = ks*32 + m, 8 bf16 (k = ks*8..+7) for row m.
    // 1 KB per component per buffer -> 6 KB total.
    __shared__ short Ah[2][512], Am_[2][512], Al[2][512];

    const int t   = threadIdx.x;
    const int bb0 = blockIdx.x * BM;
    const int g0  = blockIdx.y * NCH;  // global chunk base for this split

    // A staging: thread t -> row ar = t>>4 (0..31), k-pos ap = t&15 (1 float).
    // Global: 16 lanes cover one row's 64 B -> coalesced.
    const int ar  = t >> 4;
    const int ap  = t & 15;
    const int aof = ((ap >> 3) * 32 + ar) * 8 + (ap & 7);  // short offset

    const int lane = t & 63;
    const int wv   = t >> 6;        // wave 0..7 -> cols wv*32..+31
    const int kl   = lane >> 5;     // k-half 0/1
    const int ln   = lane & 31;

    f32x16 acc = (f32x16)0.0f;      // rows 0..31 x cols wv*32..+31

    // B short-offset for this lane's fragment: P[g][kl][wv*32+ln][8]
    unsigned ob = ((unsigned)(g0 * 2 + kl) * 256u + (unsigned)(wv * 32 + ln)) * 8u;
    const int ia = (kl * 32 + ln) * 8;

    float areg;

#define LOAD_A(G) {                                                            \
    const int kg = (G) * 16;                                                   \
    areg = zs[((size_t)(kg >> 10) * B_ + bb0 + ar) * D_ + (kg & 1023) + ap];   \
}

#define STORE_A(BUF) {                                                         \
    const unsigned short h = f2bf(areg); float r = areg - bf2f(h);             \
    const unsigned short m = f2bf(r); r = r - bf2f(m);                         \
    const unsigned short l = f2bf(r);                                          \
    Ah[BUF][aof]  = (short)h;                                                  \
    Am_[BUF][aof] = (short)m;                                                  \
    Al[BUF][aof]  = (short)l;                                                  \
}

#define LOAD_B(DH, DM, DL, OFF) {                                              \
    DH = *(const short8*)&Ph[OFF];                                             \
    DM = *(const short8*)&Pm[OFF];                                             \
    DL = *(const short8*)&Pl[OFF];                                             \
}

    // Per-acc chain order preserved exactly: hh, hm, mh, mm, hl, lh.
#define COMPUTE(BUF, RH, RM, RL) {                                             \
    const bf16x8 vbh = __builtin_bit_cast(bf16x8, RH);                         \
    const bf16x8 vbm = __builtin_bit_cast(bf16x8, RM);                         \
    const bf16x8 vbl = __builtin_bit_cast(bf16x8, RL);                         \
    const bf16x8 ah = __builtin_bit_cast(bf16x8, *(const short8*)&Ah[BUF][ia]);  \
    const bf16x8 am = __builtin_bit_cast(bf16x8, *(const short8*)&Am_[BUF][ia]); \
    const bf16x8 al = __builtin_bit_cast(bf16x8, *(const short8*)&Al[BUF][ia]);  \
    acc = MFMA(ah, vbh, acc);                                                  \
    acc = MFMA(ah, vbm, acc);                                                  \
    acc = MFMA(am, vbh, acc);                                                  \
    acc = MFMA(am, vbm, acc);                                                  \
    acc = MFMA(ah, vbl, acc);                                                  \
    acc = MFMA(al, vbh, acc);                                                  \
}

    short8 sAh, sAm, sAl, sBh, sBm, sBl;   // register-double-buffered B frags

    // Prologue: B(chunk 0) -> regs, A(chunk 0) -> LDS buf 0.
    LOAD_B(sAh, sAm, sAl, ob)
    LOAD_A(g0)
    STORE_A(0)
    __syncthreads();

#pragma unroll 1
    for (int c = 0; c < NCH; c += 2) {
        // --- chunk c: compute from LDS buf 0 with B regs sA*.
        ob += 4096;                       // next chunk's B image (+8 KB)
        LOAD_B(sBh, sBm, sBl, ob)         // prefetch B(c+1) -> regs
        LOAD_A(g0 + c + 1)                // prefetch A(c+1) -> reg
        COMPUTE(0, sAh, sAm, sAl)
        STORE_A(1)                        // split + ds_write A(c+1) -> buf 1
        __syncthreads();                  // prefetched B survives in regs

        // --- chunk c+1: compute from LDS buf 1 with B regs sB*.
        if (c + 2 < NCH) {
            ob += 4096;
            LOAD_B(sAh, sAm, sAl, ob)     // prefetch B(c+2)
            LOAD_A(g0 + c + 2)
        }
        COMPUTE(1, sBh, sBm, sBl)
        if (c + 2 < NCH) STORE_A(0)
        __syncthreads();
    }
#undef LOAD_A
#undef STORE_A
#undef LOAD_B
#undef COMPUTE

    // Epilogue: C/D layout (verified m74/m101): col = ln, row = (r&3)+8*(r>>2)+4*kl
    float* P = part + ((size_t)blockIdx.y * B_ + bb0) * H_;
    const int col = wv * 32 + ln;
#pragma unroll
    for (int r = 0; r < 16; ++r) {
        const int row0 = (r & 3) + 8 * (r >> 2) + 4 * kl;
        P[(size_t)row0 * H_ + col] = acc[r];
    }
}

// ---------------------------------------------------------------------------
// Gate+combine fused: one wave per row. x = sum(partials)+b1, exact GELU,
// logits via W2, 64-lane butterfly reduce (bit-identical on every lane ->
// every lane computes top-2; no broadcast needed), top-2 softmax, dense w,
// then fused[b,:] = wa*zs[e1,b,:] + wb*zs[e2,b,:] in the same wave.
// ---------------------------------------------------------------------------
__device__ __forceinline__ float gelu_exact(float x) {
    return 0.5f * x * (1.0f + erff(x * 0.70710678118654752f));
}

__global__ __launch_bounds__(256)
void gate_combine_kernel(const float* __restrict__ part, const float* __restrict__ b1,
                         const float* __restrict__ W2, const float* __restrict__ b2,
                         const float* __restrict__ zs, float* __restrict__ fused,
                         float* __restrict__ w_out)
{
    const int t    = threadIdx.x;
    const int wv   = t >> 6;
    const int lane = t & 63;
    const int row  = blockIdx.x * 4 + wv;

    const float* pr = part + (size_t)row * H_ + lane * 4;
    const float4 x0 = *(const float4*)pr;
    const float4 x1 = *(const float4*)(pr + (size_t)B_ * H_);
    const float4 x2 = *(const float4*)(pr + (size_t)2 * B_ * H_);
    const float4 x3 = *(const float4*)(pr + (size_t)3 * B_ * H_);
    const float4 bb = *(const float4*)&b1[lane * 4];
    const float h0 = gelu_exact(x0.x + x1.x + x2.x + x3.x + bb.x);
    const float h1 = gelu_exact(x0.y + x1.y + x2.y + x3.y + bb.y);
    const float h2 = gelu_exact(x0.z + x1.z + x2.z + x3.z + bb.z);
    const float h3 = gelu_exact(x0.w + x1.w + x2.w + x3.w + bb.w);

    float lg[8] = {0, 0, 0, 0, 0, 0, 0, 0};
    const int cb = lane * 4;
#define ACC8(HC, CI) {                                                         \
    const float4 wa_ = *(const float4*)&W2[(cb + (CI)) * 8];                   \
    const float4 wb_ = *(const float4*)&W2[(cb + (CI)) * 8 + 4];               \
    lg[0] = fmaf((HC), wa_.x, lg[0]); lg[1] = fmaf((HC), wa_.y, lg[1]);        \
    lg[2] = fmaf((HC), wa_.z, lg[2]); lg[3] = fmaf((HC), wa_.w, lg[3]);        \
    lg[4] = fmaf((HC), wb_.x, lg[4]); lg[5] = fmaf((HC), wb_.y, lg[5]);        \
    lg[6] = fmaf((HC), wb_.z, lg[6]); lg[7] = fmaf((HC), wb_.w, lg[7]);        \
}
    ACC8(h0, 0) ACC8(h1, 1) ACC8(h2, 2) ACC8(h3, 3)
#undef ACC8

#pragma unroll
    for (int off = 32; off >= 1; off >>= 1) {
#pragma unroll
        for (int i = 0; i < 8; ++i) lg[i] += __shfl_xor(lg[i], off, 64);
    }

    // Butterfly leaves bit-identical totals in every lane -> all lanes
    // compute the same top-2.
    float l[8];
#pragma unroll
    for (int i = 0; i < 8; ++i) l[i] = lg[i] + b2[i];
    int i1 = 0; float l1 = l[0];
#pragma unroll
    for (int i = 1; i < 8; ++i) if (l[i] > l1) { l1 = l[i]; i1 = i; }
    int i2 = (i1 == 0) ? 1 : 0; float l2 = l[i2];
#pragma unroll
    for (int i = 0; i < 8; ++i)
        if (i != i1 && l[i] > l2) { l2 = l[i]; i2 = i; }

    const float e  = expf(l2 - l1);
    const float dn = 1.0f + e;
    const float wa = 1.0f / dn;
    const float wb = e / dn;

    if (lane == 0) {
        float* wr = w_out + (size_t)row * M_;
#pragma unroll
        for (int i = 0; i < 8; ++i)
            wr[i] = (i == i1) ? wa : ((i == i2) ? wb : 0.0f);
    }

    // Combine: 1024 floats / row = 4 float4 per lane.
    const float4* z1 = (const float4*)(zs + ((size_t)i1 * B_ + row) * D_);
    const float4* z2 = (const float4*)(zs + ((size_t)i2 * B_ + row) * D_);
    float4* o = (float4*)(fused + (size_t)row * D_);
#pragma unroll
    for (int i = 0; i < 4; ++i) {
        const int d = lane + i * 64;
        const float4 x = z1[d];
        const float4 y = z2[d];
        o[d] = make_float4(fmaf(wa, x.x, wb * y.x),
                           fmaf(wa, x.y, wb * y.y),
                           fmaf(wa, x.z, wb * y.z),
                           fmaf(wa, x.w, wb * y.w));
    }
}

// ---------------------------------------------------------------------------
extern "C" void kernel_launch(void* const* d_in, const int* in_sizes, int n_in,
                              void* d_out, int out_size, void* d_ws, size_t ws_size,
                              hipStream_t stream)
{
    const float* zs = (const float*)d_in[0];
    const float* W1 = (const float*)d_in[1];
    const float* b1 = (const float*)d_in[2];
    const float* W2 = (const float*)d_in[3];
    const float* b2 = (const float*)d_in[4];

    float* fused = (float*)d_out;                    // [8192][1024]
    float* w_out = fused + (size_t)B_ * D_;          // [8192][8]

    // ws: part [4][8192][256] fp32 (32 MB) | Ph/Pm/Pl packed bf16 W1 (3 x 4 MB)
    float* part = (float*)d_ws;
    short* Ph = (short*)(part + (size_t)SPLITK * B_ * H_);
    const size_t PSZ = (size_t)NG * 2 * 256 * 8;     // shorts per component
    short* Pm = Ph + PSZ;
    short* Pl = Pm + PSZ;

    splitw1_kernel<<<NG, 256, 0, stream>>>(W1, Ph, Pm, Pl);
    gemm1_kernel<<<dim3(B_ / BM, SPLITK), 512, 0, stream>>>(zs, Ph, Pm, Pl, part);
    gate_combine_kernel<<<dim3(B_ / 4), 256, 0, stream>>>(part, b1, W2, b2, zs, fused, w_out);
}